// Round 1
// baseline (86.628 us; speedup 1.0000x reference)
//
#include <hip/hip_runtime.h>
#include <math.h>

#define RADIUS 5
#define DIAM   11
#define D2     121
#define CENTER 60   // RADIUS*DIAM + RADIUS

constexpr int TILE = 16;
constexpr int LT   = TILE + 2 * RADIUS;  // 26

// Binarize per reference: NaN -> 0, <1 -> 0, else keep value
__device__ __forceinline__ float binarize(float v) {
    return (isnan(v) || v < 1.0f) ? 0.0f : v;
}

__global__ __launch_bounds__(256) void crf_main(
    const float* __restrict__ x,      // [N,3,H,W]
    const float* __restrict__ y,      // [N,H,W]
    const float* __restrict__ msrc,   // [N,1,H,W]
    const float* __restrict__ mdst,   // [N,1,H,W]
    double* __restrict__ acc,         // acc[0]=numerator, acc[1]=denom
    int H, int W)
{
    __shared__ float sSig[LT][LT];
    __shared__ float sMs [LT][LT];
    __shared__ float sX0 [LT][LT];
    __shared__ float sX1 [LT][LT];
    __shared__ float sX2 [LT][LT];
    __shared__ float sExy[D2];
    __shared__ float wSum[4], wMd[4];

    const int n   = blockIdx.z;
    const int ti0 = blockIdx.y * TILE;
    const int tj0 = blockIdx.x * TILE;
    const int tid = threadIdx.y * TILE + threadIdx.x;

    // spatial-kernel table: exp(-0.5*(di^2+dj^2)/36), center forced to 0
    if (tid < D2) {
        int di = tid / DIAM - RADIUS;
        int dj = tid % DIAM - RADIUS;
        float v = __expf(-0.5f * (float)(di * di + dj * dj) * (1.0f / 36.0f));
        if (tid == CENTER) v = 0.0f;
        sExy[tid] = v;
    }

    const long long planeHW = (long long)H * W;
    const float* xn  = x    + (long long)n * 3 * planeHW;
    const float* yn  = y    + (long long)n * planeHW;
    const float* msn = msrc + (long long)n * planeHW;
    const float* mdn = mdst + (long long)n * planeHW;

    // cooperative halo load (676 elems / 256 threads)
    for (int idx = tid; idx < LT * LT; idx += 256) {
        int li = idx / LT, lj = idx % LT;
        int gi = ti0 - RADIUS + li;
        int gj = tj0 - RADIUS + lj;
        float sg = 0.f, mv = 0.f, v0 = 0.f, v1 = 0.f, v2 = 0.f;
        if (gi >= 0 && gi < H && gj >= 0 && gj < W) {
            long long p = (long long)gi * W + gj;
            sg = 1.0f / (1.0f + __expf(-yn[p]));
            mv = binarize(msn[p]);
            v0 = xn[p];
            v1 = xn[planeHW + p];
            v2 = xn[2 * planeHW + p];
        }
        sSig[li][lj] = sg;
        sMs [li][lj] = mv;
        sX0 [li][lj] = v0;
        sX1 [li][lj] = v1;
        sX2 [li][lj] = v2;
    }
    __syncthreads();

    const int li = threadIdx.y, lj = threadIdx.x;
    const int ci = li + RADIUS, cj = lj + RADIUS;
    const int gi = ti0 + li,   gj = tj0 + lj;
    const bool valid = (gi < H && gj < W);

    float lsum = 0.0f, mdb = 0.0f;
    if (valid) {
        const float c0 = sX0[ci][cj], c1 = sX1[ci][cj], c2 = sX2[ci][cj];
        const float sc = sSig[ci][cj];
        mdb = binarize(mdn[(long long)gi * W + gj]);

        for (int di = -RADIUS; di <= RADIUS; ++di) {
            const int ni = ci + di;
            #pragma unroll
            for (int dj = -RADIUS; dj <= RADIUS; ++dj) {
                const int nj = cj + dj;
                float m   = sMs[ni][nj];
                float ex  = sExy[(di + RADIUS) * DIAM + (dj + RADIUS)];
                float d0  = (sX0[ni][nj] - c0) * 10.0f;
                float d1  = (sX1[ni][nj] - c1) * 10.0f;
                float d2  = (sX2[ni][nj] - c2) * 10.0f;
                float q   = d0 * d0 + d1 * d1 + d2 * d2;
                float w   = ex * (0.9f * __expf(-0.5f * q) + 0.1f);
                float snb = sSig[ni][nj];
                float sim = (1.0f - snb) * (1.0f - sc) + snb * sc;
                lsum += w * m * (1.0f - sim);
            }
        }
        lsum *= mdb;
    }

    // block reduction: wave shuffle then 4 partials in LDS
    float a = lsum, b = mdb;
    #pragma unroll
    for (int off = 32; off > 0; off >>= 1) {
        a += __shfl_down(a, off, 64);
        b += __shfl_down(b, off, 64);
    }
    const int wave = tid >> 6, lane = tid & 63;
    if (lane == 0) { wSum[wave] = a; wMd[wave] = b; }
    __syncthreads();
    if (tid == 0) {
        float t1 = wSum[0] + wSum[1] + wSum[2] + wSum[3];
        float t2 = wMd[0] + wMd[1] + wMd[2] + wMd[3];
        atomicAdd(&acc[0], (double)t1);
        atomicAdd(&acc[1], (double)t2);
    }
}

__global__ void crf_final(const double* __restrict__ acc, float* __restrict__ out) {
    double denom = acc[1] < 1.0 ? 1.0 : acc[1];
    out[0] = (float)(acc[0] / denom);
}

extern "C" void kernel_launch(void* const* d_in, const int* in_sizes, int n_in,
                              void* d_out, int out_size, void* d_ws, size_t ws_size,
                              hipStream_t stream) {
    const float* x  = (const float*)d_in[0];
    const float* yv = (const float*)d_in[1];
    const float* ms = (const float*)d_in[2];
    const float* md = (const float*)d_in[3];
    float* out  = (float*)d_out;
    double* acc = (double*)d_ws;

    const int H = 256, W = 256;
    const int N = in_sizes[1] / (H * W);  // y is [N,H,W]

    hipMemsetAsync(acc, 0, 2 * sizeof(double), stream);

    dim3 block(TILE, TILE);
    dim3 grid((W + TILE - 1) / TILE, (H + TILE - 1) / TILE, N);
    hipLaunchKernelGGL(crf_main, grid, block, 0, stream, x, yv, ms, md, acc, H, W);
    hipLaunchKernelGGL(crf_final, dim3(1), dim3(1), 0, stream, acc, out);
}

// Round 2
// 68.604 us; speedup vs baseline: 1.2627x; 1.2627x over previous
//
#include <hip/hip_runtime.h>
#include <math.h>

#define RADIUS 5
#define DIAM   11

constexpr int TILE = 16;
constexpr int LT   = TILE + 2 * RADIUS;  // 26
constexpr int NOFF = 60;                 // positive offsets: (0,1..5), (1..5, -5..5)

// Binarize per reference: NaN -> 0, <1 -> 0, else keep value
__device__ __forceinline__ float binarize(float v) {
    return (isnan(v) || v < 1.0f) ? 0.0f : v;
}

// Pair-symmetric formulation:
//   numerator = sum over unordered pairs {p,q=p+t}, t positive offset, of
//       w(p,q) * (1 - sim(p,q)) * (ms_q*md_p + ms_p*md_q)
//   w = exp(-(di^2+dj^2)/72) * (0.9*exp(-50*|x_q-x_p|^2) + 0.1)
//   1 - sim = a + b - 2ab   (a=sig_q, b=sig_p)
//   denominator = sum of binarized md
__global__ __launch_bounds__(256) void crf_main(
    const float* __restrict__ x,      // [N,3,H,W]
    const float* __restrict__ y,      // [N,H,W]
    const float* __restrict__ msrc,   // [N,1,H,W]
    const float* __restrict__ mdst,   // [N,1,H,W]
    float2* __restrict__ partial,     // [gridX*gridY*N]
    int H, int W)
{
    __shared__ float4 sP[LT][LT];   // x0,x1,x2,sigmoid(y)
    __shared__ float2 sM[LT][LT];   // binarized ms, binarized md
    __shared__ float  sExy[NOFF];
    __shared__ float  wRedA[4], wRedB[4];

    const int n   = blockIdx.z;
    const int ti0 = blockIdx.y * TILE;
    const int tj0 = blockIdx.x * TILE;
    const int tid = threadIdx.y * TILE + threadIdx.x;

    // spatial-kernel table over positive offsets
    if (tid < NOFF) {
        int di, dj;
        if (tid < 5) { di = 0; dj = tid + 1; }
        else         { di = (tid - 5) / DIAM + 1; dj = (tid - 5) % DIAM - RADIUS; }
        sExy[tid] = __expf(-(float)(di * di + dj * dj) * (1.0f / 72.0f));
    }

    const long long planeHW = (long long)H * W;
    const float* xn  = x    + (long long)n * 3 * planeHW;
    const float* yn  = y    + (long long)n * planeHW;
    const float* msn = msrc + (long long)n * planeHW;
    const float* mdn = mdst + (long long)n * planeHW;

    // cooperative halo load (676 elems / 256 threads)
    for (int idx = tid; idx < LT * LT; idx += 256) {
        int li = idx / LT, lj = idx % LT;
        int gi = ti0 - RADIUS + li;
        int gj = tj0 - RADIUS + lj;
        float4 P = make_float4(0.f, 0.f, 0.f, 0.f);
        float2 M = make_float2(0.f, 0.f);
        if (gi >= 0 && gi < H && gj >= 0 && gj < W) {
            long long p = (long long)gi * W + gj;
            P.x = xn[p];
            P.y = xn[planeHW + p];
            P.z = xn[2 * planeHW + p];
            P.w = 1.0f / (1.0f + __expf(-yn[p]));
            M.x = binarize(msn[p]);
            M.y = binarize(mdn[p]);
        }
        sP[li][lj] = P;
        sM[li][lj] = M;
    }
    __syncthreads();

    const int ci = threadIdx.y + RADIUS, cj = threadIdx.x + RADIUS;
    const int gi = ti0 + threadIdx.y,    gj = tj0 + threadIdx.x;
    const bool valid = (gi < H && gj < W);

    float lsum = 0.0f, mdb = 0.0f;
    if (valid) {
        const float4 C  = sP[ci][cj];
        const float2 Mc = sM[ci][cj];
        const float  sc   = C.w;
        const float  c1m2 = 1.0f - 2.0f * sc;   // (1-sim) = fma(a, 1-2b, b)
        mdb = Mc.y;

        #pragma unroll
        for (int k = 0; k < NOFF; ++k) {
            int di, dj;   // constant-folded under full unroll
            if (k < 5) { di = 0; dj = k + 1; }
            else       { di = (k - 5) / DIAM + 1; dj = (k - 5) % DIAM - RADIUS; }
            const float4 P = sP[ci + di][cj + dj];
            const float2 M = sM[ci + di][cj + dj];
            float d0 = P.x - C.x, d1 = P.y - C.y, d2 = P.z - C.z;
            float u  = fmaf(d2, d2, fmaf(d1, d1, d0 * d0));
            float e  = __expf(-50.0f * u);
            float w  = sExy[k] * fmaf(0.9f, e, 0.1f);
            float oms = fmaf(P.w, c1m2, sc);            // 1 - sim
            float pm  = fmaf(Mc.x, M.y, M.x * Mc.y);    // ms_c*md_q + ms_q*md_c
            lsum = fmaf(w * oms, pm, lsum);
        }
    }

    // block reduction: wave shuffle then 4 partials in LDS
    float a = lsum, b = mdb;
    #pragma unroll
    for (int off = 32; off > 0; off >>= 1) {
        a += __shfl_down(a, off, 64);
        b += __shfl_down(b, off, 64);
    }
    const int wave = tid >> 6, lane = tid & 63;
    if (lane == 0) { wRedA[wave] = a; wRedB[wave] = b; }
    __syncthreads();
    if (tid == 0) {
        float t1 = wRedA[0] + wRedA[1] + wRedA[2] + wRedA[3];
        float t2 = wRedB[0] + wRedB[1] + wRedB[2] + wRedB[3];
        int bid = (blockIdx.z * gridDim.y + blockIdx.y) * gridDim.x + blockIdx.x;
        partial[bid] = make_float2(t1, t2);   // plain store: no init needed
    }
}

__global__ __launch_bounds__(256) void crf_final(
    const float2* __restrict__ partial, int G, float* __restrict__ out)
{
    __shared__ float wRedA[4], wRedB[4];
    float a = 0.f, b = 0.f;
    for (int i = threadIdx.x; i < G; i += 256) {
        float2 p = partial[i];
        a += p.x; b += p.y;
    }
    #pragma unroll
    for (int off = 32; off > 0; off >>= 1) {
        a += __shfl_down(a, off, 64);
        b += __shfl_down(b, off, 64);
    }
    const int wave = threadIdx.x >> 6, lane = threadIdx.x & 63;
    if (lane == 0) { wRedA[wave] = a; wRedB[wave] = b; }
    __syncthreads();
    if (threadIdx.x == 0) {
        double num   = (double)wRedA[0] + wRedA[1] + wRedA[2] + wRedA[3];
        double denom = (double)wRedB[0] + wRedB[1] + wRedB[2] + wRedB[3];
        if (denom < 1.0) denom = 1.0;
        out[0] = (float)(num / denom);
    }
}

extern "C" void kernel_launch(void* const* d_in, const int* in_sizes, int n_in,
                              void* d_out, int out_size, void* d_ws, size_t ws_size,
                              hipStream_t stream) {
    const float* x  = (const float*)d_in[0];
    const float* yv = (const float*)d_in[1];
    const float* ms = (const float*)d_in[2];
    const float* md = (const float*)d_in[3];
    float* out      = (float*)d_out;
    float2* partial = (float2*)d_ws;

    const int H = 256, W = 256;
    const int N = in_sizes[1] / (H * W);  // y is [N,H,W]

    dim3 block(TILE, TILE);
    dim3 grid((W + TILE - 1) / TILE, (H + TILE - 1) / TILE, N);
    const int G = grid.x * grid.y * grid.z;

    hipLaunchKernelGGL(crf_main, grid, block, 0, stream, x, yv, ms, md, partial, H, W);
    hipLaunchKernelGGL(crf_final, dim3(1), dim3(256), 0, stream, partial, G, out);
}